// Round 6
// baseline (898.391 us; speedup 1.0000x reference)
//
#include <hip/hip_runtime.h>
#include <math.h>

#define S_   400
#define B_   16
#define T_   32
#define H_   256
#define A_   100
#define G_   50
#define VF_  100
#define V_   50000
#define BV_  50050

#define L2E   1.44269504088896f
#define L2E2  2.88539008177793f

// ---- ws offsets (floats) ----
#define WS_H0S   0          // [2][256][16] h-major state, parity buffered
#define WS_C0S   8192
#define WS_H1S   16384
#define WS_C1S   24576
#define WS_Y0    32768      // [32][256][16] layer0 outputs (h-major)
#define WS_OD    163840     // [32][256][16] layer1 outputs (h-major)
#define WS_WT0   294912     // [256][1024] permuted k-major w_hh0
#define WS_WTI1  557056     // [256][1024] permuted k-major w_ih1
#define WS_WTH1  819200     // [256][1024] permuted k-major w_hh1
#define WS_WODT  1081344    // [256][100]  W_attn[:,512:768]^T
#define WS_WV1T  1106944    // [768][100]  W_v1^T
#define WS_WRT   1183744    // [512][256]  W_reduce^T
#define WS_BASE2 1314816    // [16][400][2][56]  (enc@Wattn + b_attn)*2log2e, padded halves
#define WS_ODP3  2031616    // [16][32][100] float4 {odp*2log2e, wc*2log2e, -2*wo, 0}
#define WS_ATTN  2236416    // [16][32][400]
#define WS_H1B   2441216    // [512][128] bf16 (stored as shorts) = 32768 float slots
#define WS_PGEN  2473984    // [512]
#define WS_VSUM  2474496    // [512]
#define WS_TOTAL 2475008

// ---- out offsets (floats) ----
#define OUT_CL   25625600
#define OUT_COV  25626112
#define OUT_HID  25632512
#define OUT_CELL 25640704
// first 8*512*512 floats of out are used as ctx-partial scratch (overwritten by vocab pass B later)
#define CTXP_SZ  262144

typedef __attribute__((ext_vector_type(8))) short bf16x8;
typedef __attribute__((ext_vector_type(4))) float f32x4;

__device__ __forceinline__ float fexp2(float x){ return __builtin_amdgcn_exp2f(x); }
__device__ __forceinline__ float frcp (float x){ return __builtin_amdgcn_rcpf(x); }
__device__ __forceinline__ float sigm (float x){ return frcp(1.f + fexp2(-L2E*x)); }
__device__ __forceinline__ float tanhx(float x){ return fmaf(-2.f, frcp(1.f + fexp2(L2E2*x)), 1.f); }
__device__ __forceinline__ short cvt_bf16(float x){
  unsigned u = __float_as_uint(x);
  u += 0x7FFFu + ((u >> 16) & 1u);
  return (short)(u >> 16);
}

__device__ __forceinline__ float bredSum(float v, float* red){
  #pragma unroll
  for (int m = 32; m >= 1; m >>= 1) v += __shfl_xor(v, m);
  __syncthreads();
  if ((threadIdx.x & 63) == 0) red[threadIdx.x >> 6] = v;
  __syncthreads();
  float r = 0.f;
  int nw = blockDim.x >> 6;
  for (int k = 0; k < nw; ++k) r += red[k];
  return r;
}

// ---------------- prep (transposes/zero) + enc_base merged into one dispatch ----------------
__global__ __launch_bounds__(256) void k_prep_enc(const float* __restrict__ w_hh0,
    const float* __restrict__ w_ih1, const float* __restrict__ w_hh1,
    const float* __restrict__ W_attn, const float* __restrict__ W_v1,
    const float* __restrict__ W_reduce, const float* __restrict__ enc,
    const float* __restrict__ b_attn, float* __restrict__ ws){
  int bx = blockIdx.x, tid = threadIdx.x;
  __shared__ float tile[64*65];
  __shared__ float encs[16][132];
  __shared__ float was[50][132];
  if (bx < 627){
    if (bx < 192){
      int m = bx >> 6, t6 = bx & 63;
      int kb = t6 & 3, cb = t6 >> 2;
      const float* src = (m == 0) ? w_hh0 : (m == 1) ? w_ih1 : w_hh1;
      int dstoff = (m == 0) ? WS_WT0 : (m == 1) ? WS_WTI1 : WS_WTH1;
      for (int o = tid; o < 4096; o += 256){
        int cc = o >> 6, kk = o & 63;
        int c = cb*64 + cc;
        int j;
        if (m == 0){ int w = c >> 6, l = c & 63; j = (l>>4)*256 + w*16 + (l&15); }
        else       { int u = c >> 5, idx = c & 31; j = (idx>>3)*256 + u*8 + (idx&7); }
        tile[cc*65 + kk] = src[j*256 + kb*64 + kk];
      }
      __syncthreads();
      for (int o = tid; o < 4096; o += 256){
        int kk = o >> 6, cc = o & 63;
        ws[dstoff + (kb*64 + kk)*1024 + cb*64 + cc] = tile[cc*65 + kk];
      }
      return;
    }
    if (bx < 224){
      int t6 = bx - 192;      // W_reduce [256 j][512 k] -> WRT [512 k][256 j]
      int kb = t6 & 7, jb = t6 >> 3;
      for (int o = tid; o < 4096; o += 256){
        int jj = o >> 6, kk = o & 63;
        tile[jj*65 + kk] = W_reduce[(jb*64 + jj)*512 + kb*64 + kk];
      }
      __syncthreads();
      for (int o = tid; o < 4096; o += 256){
        int kk = o >> 6, jj = o & 63;
        ws[WS_WRT + (kb*64 + kk)*256 + jb*64 + jj] = tile[jj*65 + kk];
      }
      return;
    }
    int i = (bx - 224)*256 + tid;
    if (i < 25600){ int k = i/100, a = i%100; ws[WS_WODT + i] = W_attn[a*769 + 512 + k]; return; }
    i -= 25600;
    if (i < 76800){ int k = i/100, f = i%100; ws[WS_WV1T + i] = W_v1[f*768 + k]; return; }
    i -= 76800;
    if (i < 512){ ws[WS_VSUM + i] = 0.f; return; }
    return;
  }
  // ---- enc_base: (output_enc @ W_attn[:, :512]^T + b_attn)*2log2e -> [b][s][half][56] ----
  int r = bx - 627;                      // 800 = st + 25*(ah + 2*b)
  int st = r % 25, rem = r / 25;
  int ah = rem & 1, b = rem >> 1;
  int s_base = st*16;
  bool act = tid < 200;
  int sg = tid & 7, ag = tid >> 3;
  int sl = sg*2, al = ag*2;
  float acc00=0.f, acc01=0.f, acc10=0.f, acc11=0.f;
  for (int kc = 0; kc < 4; ++kc){
    int k0 = kc*128;
    __syncthreads();
    for (int o = tid; o < 512; o += 256){
      int rr = o >> 5, c4 = (o & 31)*4;
      float4 v = *(const float4*)(enc + ((s_base + rr)*B_ + b)*512 + k0 + c4);
      *(float4*)&encs[rr][c4] = v;
    }
    for (int o = tid; o < 6400; o += 256){
      int rr = o >> 7, c = o & 127;
      was[rr][c] = W_attn[(ah*50 + rr)*769 + k0 + c];
    }
    __syncthreads();
    if (act){
      for (int k = 0; k < 128; ++k){
        float e0 = encs[sl][k], e1 = encs[sl+1][k];
        float w0 = was[al][k],  w1 = was[al+1][k];
        acc00 = fmaf(e0, w0, acc00); acc01 = fmaf(e0, w1, acc01);
        acc10 = fmaf(e1, w0, acc10); acc11 = fmaf(e1, w1, acc11);
      }
    }
  }
  if (act){
    int a = ah*50 + al, s = s_base + sl;
    float b0 = b_attn[a], b1 = b_attn[a+1];
    float* bpp = ws + WS_BASE2;
    bpp[((b*400 + s  )*2 + ah)*56 + al    ] = (acc00 + b0) * L2E2;
    bpp[((b*400 + s  )*2 + ah)*56 + al + 1] = (acc01 + b1) * L2E2;
    bpp[((b*400 + s+1)*2 + ah)*56 + al    ] = (acc10 + b0) * L2E2;
    bpp[((b*400 + s+1)*2 + ah)*56 + al + 1] = (acc11 + b1) * L2E2;
  }
}

// ---------------- encoder state reduce (writes h-major state) ----------------
__global__ __launch_bounds__(256) void k_reduce_enc(const float* __restrict__ he,
    const float* __restrict__ ce, const float* __restrict__ b_reduce, float* __restrict__ ws){
  int bx = blockIdx.x;            // 32 blocks: l = bx>>4, b = bx&15
  int l = bx >> 4, b = bx & 15, j = threadIdx.x;
  const float* wrt = ws + WS_WRT;
  const float* h_a = he + (l*B_ + b)*H_;
  const float* h_b = he + ((l+2)*B_ + b)*H_;
  const float* c_a = ce + (l*B_ + b)*H_;
  const float* c_b = ce + ((l+2)*B_ + b)*H_;
  float ah = b_reduce[j], ac = b_reduce[j];
  for (int k = 0; k < 256; ++k){
    float w0 = wrt[k*256 + j];
    float w1 = wrt[(256+k)*256 + j];
    ah += w0*h_a[k] + w1*h_b[k];
    ac += w0*c_a[k] + w1*c_b[k];
  }
  if (l == 0){ ws[WS_H0S + j*16 + b] = ah; ws[WS_C0S + j*16 + b] = ac; }
  else       { ws[WS_H1S + j*16 + b] = ah; ws[WS_C1S + j*16 + b] = ac; }
}

// ---------------- LSTM phase p: WGs 0-15 layer0 step p, WGs 16-47 layer1 step p-1 ----------------
__global__ __launch_bounds__(256, 1) void k_lstm2(const float* __restrict__ input_dec,
    const float* __restrict__ w_ih0, const float* __restrict__ b_ih0, const float* __restrict__ b_hh0,
    const float* __restrict__ b_ih1, const float* __restrict__ b_hh1,
    float* __restrict__ ws, float* __restrict__ out, int p){
  int wgs = blockIdx.x;
  int tid = threadIdx.x;
  __shared__ float hs[4096];
  __shared__ float ys[4096];
  __shared__ float gv[1088];
  __shared__ float xs[16];
  if (wgs < 16){
    if (p >= T_) return;
    int w = wgs;
    int par = p & 1, npar = par ^ 1;
    for (int o = tid; o < 4096; o += 256) hs[o] = ws[WS_H0S + par*4096 + o];
    if (tid < 16) xs[tid] = input_dec[p*16 + tid];
    __syncthreads();
    int bg = tid >> 6, l = tid & 63;
    int g = l >> 4, hh = l & 15;
    int j = g*256 + w*16 + hh;
    float bias = b_ih0[j] + b_hh0[j];
    float wih = w_ih0[j];
    float x0 = xs[bg*4+0], x1 = xs[bg*4+1], x2 = xs[bg*4+2], x3 = xs[bg*4+3];
    float a0 = fmaf(x0, wih, bias);
    float a1 = fmaf(x1, wih, bias);
    float a2 = fmaf(x2, wih, bias);
    float a3 = fmaf(x3, wih, bias);
    const float* wp = ws + WS_WT0 + w*64 + l;
    #pragma unroll 32
    for (int k = 0; k < 256; ++k){
      float wv = wp[k*1024];
      float4 hv = *(const float4*)&hs[k*16 + bg*4];
      a0 = fmaf(wv, hv.x, a0); a1 = fmaf(wv, hv.y, a1);
      a2 = fmaf(wv, hv.z, a2); a3 = fmaf(wv, hv.w, a3);
    }
    int gb = (g*16 + hh)*17 + bg*4;
    gv[gb+0] = a0; gv[gb+1] = a1; gv[gb+2] = a2; gv[gb+3] = a3;
    __syncthreads();
    int b = tid & 15, h2 = tid >> 4;
    float gi = gv[(0*16+h2)*17 + b], gf = gv[(1*16+h2)*17 + b];
    float gg = gv[(2*16+h2)*17 + b], go = gv[(3*16+h2)*17 + b];
    int hidx = w*16 + h2;
    float cold = ws[WS_C0S + par*4096 + hidx*16 + b];
    float ig = sigm(gi), fg = sigm(gf), gt = tanhx(gg), og = sigm(go);
    float cn = fmaf(fg, cold, ig*gt);
    float hn = og * tanhx(cn);
    ws[WS_C0S + npar*4096 + hidx*16 + b] = cn;
    ws[WS_H0S + npar*4096 + hidx*16 + b] = hn;
    ws[WS_Y0 + p*4096 + hidx*16 + b] = hn;
    if (p == T_-1){
      out[OUT_HID  + b*256 + hidx] = hn;
      out[OUT_CELL + b*256 + hidx] = cn;
    }
  } else {
    int q = p - 1;
    if (q < 0) return;
    int u = wgs - 16;
    int par = q & 1, npar = par ^ 1;
    for (int o = tid; o < 4096; o += 256){
      ys[o] = ws[WS_Y0 + q*4096 + o];
      hs[o] = ws[WS_H1S + par*4096 + o];
    }
    __syncthreads();
    int bg = tid >> 5, idx = tid & 31;
    int g = idx >> 3, hh = idx & 7;
    int j = g*256 + u*8 + hh;
    float bias = b_ih1[j] + b_hh1[j];
    float ai0 = bias, ah0 = 0.f, ai1 = bias, ah1 = 0.f;
    const float* wip = ws + WS_WTI1 + u*32 + idx;
    const float* whp = ws + WS_WTH1 + u*32 + idx;
    #pragma unroll 16
    for (int k = 0; k < 256; ++k){
      float wi = wip[k*1024];
      float wh = whp[k*1024];
      float2 yv = *(const float2*)&ys[k*16 + bg*2];
      float2 hv = *(const float2*)&hs[k*16 + bg*2];
      ai0 = fmaf(wi, yv.x, ai0); ai1 = fmaf(wi, yv.y, ai1);
      ah0 = fmaf(wh, hv.x, ah0); ah1 = fmaf(wh, hv.y, ah1);
    }
    int gb = g*136 + hh*17 + bg*2;
    gv[gb+0] = ai0 + ah0; gv[gb+1] = ai1 + ah1;
    __syncthreads();
    if (tid < 128){
      int b = tid & 15, h2 = (tid >> 4) & 7;
      float gi = gv[0*136 + h2*17 + b], gf = gv[1*136 + h2*17 + b];
      float gg = gv[2*136 + h2*17 + b], go = gv[3*136 + h2*17 + b];
      int hidx = u*8 + h2;
      float cold = ws[WS_C1S + par*4096 + hidx*16 + b];
      float ig = sigm(gi), fg = sigm(gf), gt = tanhx(gg), og = sigm(go);
      float cn = fmaf(fg, cold, ig*gt);
      float hn = og * tanhx(cn);
      ws[WS_C1S + npar*4096 + hidx*16 + b] = cn;
      ws[WS_H1S + npar*4096 + hidx*16 + b] = hn;
      ws[WS_OD + q*4096 + hidx*16 + b] = hn;
      if (q == T_-1){
        out[OUT_HID  + 4096 + b*256 + hidx] = hn;
        out[OUT_CELL + 4096 + b*256 + hidx] = cn;
      }
    }
  }
}

// ---------------- odp3[b][t][a] = float4{(od@WODT)*2log2e, wc*2log2e, -2*wo, 0} ----------------
__global__ __launch_bounds__(256) void k_odp(const float* __restrict__ W_attn,
    const float* __restrict__ wout_g, float* __restrict__ ws){
  int row = blockIdx.x;        // 512 = t*16+b
  int t = row >> 4, b = row & 15;
  int tid = threadIdx.x;
  __shared__ float odl[256];
  odl[tid] = ws[WS_OD + t*4096 + tid*16 + b];
  __syncthreads();
  if (tid < 100){
    float acc = 0.f;
    for (int k = 0; k < 256; ++k) acc = fmaf(ws[WS_WODT + k*100 + tid], odl[k], acc);
    float wc2 = W_attn[tid*769 + 768] * L2E2;
    float wo2 = -2.f * wout_g[tid];
    float4* o3 = (float4*)(ws + WS_ODP3);
    o3[(b*32 + t)*100 + tid] = make_float4(acc * L2E2, wc2, wo2, 0.f);
  }
}

// ---------------- attention recurrence v4: one WG per batch, SGPR-uniform odp3,
// packed ba rows, cov in registers, 2 barriers/step ----------------
__global__ __launch_bounds__(1024) void k_attn(const float* __restrict__ amask,
    const float* __restrict__ wout_g, float* __restrict__ out, float* __restrict__ ws){
  int b = blockIdx.x;
  int tid = threadIdx.x;
  int wv = tid >> 6, l = tid & 63;
  int half = wv & 1, sblk = wv >> 1;
  int s = sblk*64 + l;
  bool valid = (sblk < 7) && (s < 400);
  bool even = (half == 0);
  __shared__ float eh[2][400];
  __shared__ float den[2], cls[2];
  if (tid < 2){ den[tid] = 0.f; cls[tid] = 0.f; }
  float woSum = 0.f;
  #pragma unroll 10
  for (int a = 0; a < 100; ++a) woSum += wout_g[a];
  float amL = valid ? amask[s*16 + b] * L2E : 0.f;
  float cov = 0.f;
  int srow = valid ? s : 0;
  const float* bp = ws + WS_BASE2 + (size_t)((b*400 + srow)*2 + half)*56;
  float ba[50];
  #pragma unroll
  for (int i = 0; i < 50; ++i) ba[i] = bp[i];
  int a0u = __builtin_amdgcn_readfirstlane(half*50);
  const float4* o3 = (const float4*)(ws + WS_ODP3) + (size_t)(b*32)*100 + a0u;
  __syncthreads();

  for (int t = 0; t < T_; ++t){
    int par = t & 1;
    float ep0 = 0.f, ep1 = 0.f;
    #pragma unroll
    for (int i = 0; i < 50; i += 2){
      float4 qa = o3[t*100 + i];
      float4 qb = o3[t*100 + i + 1];
      float xa = fmaf(qa.y, cov, ba[i]   + qa.x);
      float xb = fmaf(qb.y, cov, ba[i+1] + qb.x);
      ep0 = fmaf(qa.z, frcp(1.f + fexp2(xa)), ep0);
      ep1 = fmaf(qb.z, frcp(1.f + fexp2(xb)), ep1);
    }
    if (valid) eh[half][s] = ep0 + ep1;
    __syncthreads();                      // A: eh ready
    float ex = 0.f;
    if (valid){
      float et = woSum + eh[0][s] + eh[1][s];
      ex = fexp2(fmaf(et, L2E, amL));
    }
    float ps = ex;
    #pragma unroll
    for (int m = 32; m >= 1; m >>= 1) ps += __shfl_xor(ps, m);
    if (even && l == 0) atomicAdd(&den[par], ps);
    if (tid == 0 && t > 0){
      out[OUT_CL + (t-1)*16 + b] = cls[par^1];
      cls[par^1] = 0.f;
      den[par^1] = 0.f;
    }
    __syncthreads();                      // B: den ready
    float inv = frcp(den[par]);
    float at = ex * inv;
    float cl = fminf(at, cov);
    cov += at;
    float p2 = cl;
    #pragma unroll
    for (int m = 32; m >= 1; m >>= 1) p2 += __shfl_xor(p2, m);
    if (even && l == 0) atomicAdd(&cls[par], p2);
    if (even && valid) ws[WS_ATTN + (b*32 + t)*400 + s] = at;
  }
  __syncthreads();
  if (tid == 0) out[OUT_CL + 31*16 + b] = cls[1];
  if (even && valid) out[OUT_COV + s*16 + b] = cov;
}

// ---------------- context partials into out-scratch: ctxp[sc][t*16+b][512] ----------------
__global__ __launch_bounds__(256) void k_ctx(const float* __restrict__ enc,
    const float* __restrict__ ws, float* __restrict__ ctxp){
  int b = blockIdx.x, jh = blockIdx.y, sc = blockIdx.z;   // (16,2,8)
  int tid = threadIdx.x;
  __shared__ float at[32*52];
  for (int o = tid; o < 1600; o += 256){
    int t = o/50, s2 = o%50;
    at[t*52 + s2] = ws[WS_ATTN + (b*32 + t)*400 + sc*50 + s2];
  }
  __syncthreads();
  int j = jh*256 + tid;
  float acc[32];
  #pragma unroll
  for (int t = 0; t < 32; ++t) acc[t] = 0.f;
  for (int s2 = 0; s2 < 50; ++s2){
    float evv = enc[((sc*50 + s2)*16 + b)*512 + j];
    #pragma unroll
    for (int t = 0; t < 32; ++t) acc[t] = fmaf(at[t*52 + s2], evv, acc[t]);
  }
  #pragma unroll
  for (int t = 0; t < 32; ++t)
    ctxp[sc*CTXP_SZ + (t*16 + b)*512 + j] = acc[t];
}

// ---------------- pgen + h1 (vocab hidden, bf16 padded) per (t,b) ----------------
__global__ __launch_bounds__(256) void k_pgen_h1(const float* __restrict__ input_dec,
    const float* __restrict__ emb, const float* __restrict__ b_v1,
    const float* __restrict__ W_pgen, const float* __restrict__ b_pgen,
    const float* __restrict__ ctxp, float* __restrict__ ws){
  int row = blockIdx.x, tid = threadIdx.x;
  int t = row >> 4, b = row & 15;
  __shared__ float pv[768], el[50], red[16];
  pv[tid] = ws[WS_OD + t*4096 + tid*16 + b];
  float c0 = 0.f, c1 = 0.f;
  #pragma unroll
  for (int sc = 0; sc < 8; ++sc){
    c0 += ctxp[sc*CTXP_SZ + row*512 + tid];
    c1 += ctxp[sc*CTXP_SZ + row*512 + 256 + tid];
  }
  pv[256 + tid] = c0;
  pv[512 + tid] = c1;
  int tok = (int)input_dec[row];
  if (tid < 50) el[tid] = emb[tok*50 + tid];
  __syncthreads();
  float p = 0.f;
  for (int k = tid; k < 818; k += 256){
    float x = (k < 512) ? pv[256 + k] : (k < 768) ? pv[k - 512] : el[k - 768];
    p = fmaf(W_pgen[k], x, p);
  }
  p = bredSum(p, red);
  if (tid == 0) ws[WS_PGEN + row] = sigm(p + b_pgen[0]);
  short* hb = (short*)(ws + WS_H1B);
  if (tid < 100){
    float acc = b_v1[tid];
    for (int k = 0; k < 768; ++k) acc = fmaf(ws[WS_WV1T + k*100 + tid], pv[k], acc);
    hb[row*128 + tid] = cvt_bf16(acc);
  } else if (tid < 128){
    hb[row*128 + tid] = 0;
  }
}

// ---------------- vocab GEMM via MFMA: shared frag loader ----------------
__device__ __forceinline__ void load_bfrags(const float* __restrict__ W_v2,
    const float* __restrict__ b_v2, int v0, int lane_m, int lq,
    bf16x8 bf[4][4], float bias[4], int vv[4]){
  #pragma unroll
  for (int nt = 0; nt < 4; ++nt){
    int v = v0 + nt*16 + lane_m;
    vv[nt] = v;
    bool vok = v < V_;
    bias[nt] = vok ? b_v2[v] : 0.f;
    const float* wp = W_v2 + (size_t)v*100;
    #pragma unroll
    for (int kk = 0; kk < 4; ++kk){
      int k0 = kk*32 + lq*8;
      float x[8];
      if (vok && kk < 3){
        float4 p0 = *(const float4*)(wp + k0);
        float4 p1 = *(const float4*)(wp + k0 + 4);
        x[0]=p0.x; x[1]=p0.y; x[2]=p0.z; x[3]=p0.w;
        x[4]=p1.x; x[5]=p1.y; x[6]=p1.z; x[7]=p1.w;
      } else if (vok && k0 == 96){
        float4 p0 = *(const float4*)(wp + 96);
        x[0]=p0.x; x[1]=p0.y; x[2]=p0.z; x[3]=p0.w;
        x[4]=0.f; x[5]=0.f; x[6]=0.f; x[7]=0.f;
      } else {
        #pragma unroll
        for (int e = 0; e < 8; ++e) x[e] = 0.f;
      }
      bf16x8 r;
      #pragma unroll
      for (int e = 0; e < 8; ++e) r[e] = cvt_bf16(x[e]);
      bf[nt][kk] = r;
    }
  }
}

// ---------------- pass A: per-row exp2-sums of logits (no materialization) ----------------
__global__ __launch_bounds__(256) void k_vsum(const float* __restrict__ W_v2,
    const float* __restrict__ b_v2, float* __restrict__ ws){
  int tid = threadIdx.x;
  int wave = tid >> 6, l = tid & 63;
  int lane_m = l & 15, lq = l >> 4;
  int v0 = blockIdx.x*256 + wave*64;
  int r0base = blockIdx.y*256;
  __shared__ float rsum[256];
  for (int o = tid; o < 256; o += 256) rsum[o] = 0.f;
  bf16x8 bf[4][4];
  float bias[4];
  int vv[4];
  load_bfrags(W_v2, b_v2, v0, lane_m, lq, bf, bias, vv);
  __syncthreads();
  const short* hws = (const short*)(ws + WS_H1B);
  for (int rg = 0; rg < 16; ++rg){
    int r0 = r0base + rg*16;
    bf16x8 af[4];
    #pragma unroll
    for (int kk = 0; kk < 4; ++kk)
      af[kk] = *(const bf16x8*)(hws + (r0 + lane_m)*128 + kk*32 + lq*8);
    float es[4] = {0.f, 0.f, 0.f, 0.f};
    #pragma unroll
    for (int nt = 0; nt < 4; ++nt){
      f32x4 c = {bias[nt], bias[nt], bias[nt], bias[nt]};
      #pragma unroll
      for (int kk = 0; kk < 4; ++kk)
        c = __builtin_amdgcn_mfma_f32_16x16x32_bf16(af[kk], bf[nt][kk], c, 0, 0, 0);
      if (vv[nt] < V_){
        #pragma unroll
        for (int j = 0; j < 4; ++j) es[j] += fexp2(c[j] * L2E);
      }
    }
    #pragma unroll
    for (int m = 1; m <= 8; m <<= 1){
      #pragma unroll
      for (int j = 0; j < 4; ++j) es[j] += __shfl_xor(es[j], m);
    }
    if (lane_m == 0){
      #pragma unroll
      for (int j = 0; j < 4; ++j)
        atomicAdd(&rsum[rg*16 + lq*4 + j], es[j]);
    }
  }
  __syncthreads();
  if (tid < 256) atomicAdd(ws + WS_VSUM + r0base + tid, rsum[tid]);
}

// ---------------- pass B: recompute logits, write softmax*pgen via LDS-staged coalesced stores ----------------
__global__ __launch_bounds__(256) void k_vwrite(const float* __restrict__ W_v2,
    const float* __restrict__ b_v2, const float* __restrict__ ws, float* __restrict__ out){
  int tid = threadIdx.x;
  int wave = tid >> 6, l = tid & 63;
  int lane_m = l & 15, lq = l >> 4;
  int vblock0 = blockIdx.x*256;
  int v0 = vblock0 + wave*64;
  int r0base = blockIdx.y*128;
  __shared__ float scs[128];
  __shared__ float stg[16][260];
  if (tid < 128){
    int r = r0base + tid;
    scs[tid] = ws[WS_PGEN + r] / ws[WS_VSUM + r];
  }
  bf16x8 bf[4][4];
  float bias[4];
  int vv[4];
  load_bfrags(W_v2, b_v2, v0, lane_m, lq, bf, bias, vv);
  __syncthreads();
  const short* hws = (const short*)(ws + WS_H1B);
  int limit = BV_ - vblock0;            // valid col count in [0,256]
  if (limit > 256) limit = 256;
  for (int rg = 0; rg < 8; ++rg){
    int r0 = r0base + rg*16;
    bf16x8 af[4];
    #pragma unroll
    for (int kk = 0; kk < 4; ++kk)
      af[kk] = *(const bf16x8*)(hws + (r0 + lane_m)*128 + kk*32 + lq*8);
    #pragma unroll
    for (int nt = 0; nt < 4; ++nt){
      f32x4 c = {bias[nt], bias[nt], bias[nt], bias[nt]};
      #pragma unroll
      for (int kk = 0; kk < 4; ++kk)
        c = __builtin_amdgcn_mfma_f32_16x16x32_bf16(af[kk], bf[nt][kk], c, 0, 0, 0);
      bool gen = vv[nt] < V_;
      #pragma unroll
      for (int j = 0; j < 4; ++j){
        int rloc = lq*4 + j;
        float p = gen ? fexp2(c[j] * L2E) * scs[rg*16 + rloc] : 0.f;
        stg[rloc][wave*64 + nt*16 + lane_m] = p;
      }
    }
    __syncthreads();
    #pragma unroll
    for (int rep = 0; rep < 4; ++rep){
      int o = rep*256 + tid;
      int rr = o >> 6, c4 = (o & 63)*4;
      size_t base = (size_t)(r0base + rg*16 + rr)*BV_ + vblock0;
      if (c4 + 4 <= limit){
        float4 val = *(const float4*)&stg[rr][c4];
        *(float4*)&out[base + c4] = val;
      } else {
        for (int e = 0; e < 4; ++e)
          if (c4 + e < limit) out[base + c4 + e] = stg[rr][c4 + e];
      }
    }
    __syncthreads();
  }
}

// ---------------- copy-distribution scatter ----------------
__global__ __launch_bounds__(256) void k_scatter(const int* __restrict__ real_index,
    const float* __restrict__ ws, float* __restrict__ out){
  int i = blockIdx.x*256 + threadIdx.x;   // 16*32*400
  int b = i / 12800, r = i % 12800, t = r / 400, s = r % 400;
  float at = ws[WS_ATTN + i];
  float w = 1.f - ws[WS_PGEN + t*16 + b];
  int col = real_index[s*16 + b];
  atomicAdd(out + (size_t)(t*16 + b)*BV_ + col, at*w);
}

extern "C" void kernel_launch(void* const* d_in, const int* in_sizes, int n_in,
                              void* d_out, int out_size, void* d_ws, size_t ws_size,
                              hipStream_t stream){
  const float* output_enc = (const float*)d_in[0];
  const int*   real_index = (const int*)d_in[1];
  const float* input_dec  = (const float*)d_in[3];
  const float* hidden_enc = (const float*)d_in[4];
  const float* cell_enc   = (const float*)d_in[5];
  const float* att_mask   = (const float*)d_in[6];
  const float* emb        = (const float*)d_in[7];
  const float* W_reduce   = (const float*)d_in[8];
  const float* b_reduce   = (const float*)d_in[9];
  const float* w_ih0      = (const float*)d_in[10];
  const float* w_hh0      = (const float*)d_in[11];
  const float* b_ih0      = (const float*)d_in[12];
  const float* b_hh0      = (const float*)d_in[13];
  const float* w_ih1      = (const float*)d_in[14];
  const float* w_hh1      = (const float*)d_in[15];
  const float* b_ih1      = (const float*)d_in[16];
  const float* b_hh1      = (const float*)d_in[17];
  const float* W_attn     = (const float*)d_in[18];
  const float* b_attn     = (const float*)d_in[19];
  const float* w_attn_out = (const float*)d_in[20];
  const float* W_v1       = (const float*)d_in[21];
  const float* b_v1       = (const float*)d_in[22];
  const float* W_v2       = (const float*)d_in[23];
  const float* b_v2       = (const float*)d_in[24];
  const float* W_pgen     = (const float*)d_in[25];
  const float* b_pgen     = (const float*)d_in[26];
  float* out = (float*)d_out;
  float* ws  = (float*)d_ws;
  if (ws_size < (size_t)WS_TOTAL * sizeof(float)) return;

  k_prep_enc<<<dim3(1427), dim3(256), 0, stream>>>(w_hh0, w_ih1, w_hh1, W_attn, W_v1,
                                                   W_reduce, output_enc, b_attn, ws);
  k_reduce_enc<<<dim3(32), dim3(256), 0, stream>>>(hidden_enc, cell_enc, b_reduce, ws);
  for (int p = 0; p <= T_; ++p)
    k_lstm2<<<dim3(48), dim3(256), 0, stream>>>(input_dec, w_ih0, b_ih0, b_hh0,
                                                b_ih1, b_hh1, ws, out, p);
  k_odp<<<dim3(512), dim3(256), 0, stream>>>(W_attn, w_attn_out, ws);
  k_attn<<<dim3(16), dim3(1024), 0, stream>>>(att_mask, w_attn_out, out, ws);
  k_ctx<<<dim3(16, 2, 8), dim3(256), 0, stream>>>(output_enc, ws, out);
  k_pgen_h1<<<dim3(512), dim3(256), 0, stream>>>(input_dec, emb, b_v1, W_pgen, b_pgen, out, ws);
  k_vsum<<<dim3(196, 2), dim3(256), 0, stream>>>(W_v2, b_v2, ws);
  k_vwrite<<<dim3(196, 4), dim3(256), 0, stream>>>(W_v2, b_v2, ws, out);
  k_scatter<<<dim3(800), dim3(256), 0, stream>>>(real_index, ws, out);
}

// Round 7
// 746.140 us; speedup vs baseline: 1.2041x; 1.2041x over previous
//
#include <hip/hip_runtime.h>
#include <math.h>

#define S_   400
#define B_   16
#define T_   32
#define H_   256
#define A_   100
#define G_   50
#define VF_  100
#define V_   50000
#define BV_  50050

#define L2E   1.44269504088896f
#define L2E2  2.88539008177793f

// ---- ws offsets (floats) ----
#define WS_H0S   0          // [2][256][16] h-major state, parity buffered
#define WS_C0S   8192
#define WS_H1S   16384
#define WS_C1S   24576
#define WS_Y0    32768      // [32][256][16] layer0 outputs (h-major)
#define WS_OD    163840     // [32][256][16] layer1 outputs (h-major)
#define WS_WT0   294912     // [256][1024] k-major w_hh0, col c -> j=(c&3)*256+(c>>2)
#define WS_WTI1  557056     // [256][1024] k-major w_ih1 (same col map)
#define WS_WTH1  819200     // [256][1024] k-major w_hh1 (same col map)
#define WS_WODT  1081344    // [256][100]  W_attn[:,512:768]^T
#define WS_WV1T  1106944    // [768][100]  W_v1^T
#define WS_WRT   1183744    // [512][256]  W_reduce^T
#define WS_BASE2 1314816    // [16][50][400] uint: packed bf16 pair (a=2p2, 2p2+1), pre-scaled by 2log2e
#define WS_ODP2  1634816    // [32*16][100] (od@WODT)*2log2e
#define WS_ATTN  1686016    // [16][32][400]
#define WS_H1B   1890816    // [512][128] bf16 (stored as shorts) = 32768 float slots
#define WS_PGEN  1923584    // [512]
#define WS_VSUM  1924096    // [512]
#define WS_TOTAL 1924608

// ---- out offsets (floats) ----
#define OUT_CL   25625600
#define OUT_COV  25626112
#define OUT_HID  25632512
#define OUT_CELL 25640704
// first 8*512*512 floats of out are used as ctx-partial scratch (overwritten by vocab pass B later)
#define CTXP_SZ  262144

typedef __attribute__((ext_vector_type(8))) short bf16x8;
typedef __attribute__((ext_vector_type(4))) float f32x4;

__device__ __forceinline__ float fexp2(float x){ return __builtin_amdgcn_exp2f(x); }
__device__ __forceinline__ float frcp (float x){ return __builtin_amdgcn_rcpf(x); }
__device__ __forceinline__ float sigm (float x){ return frcp(1.f + fexp2(-L2E*x)); }
__device__ __forceinline__ float tanhx(float x){ return fmaf(-2.f, frcp(1.f + fexp2(L2E2*x)), 1.f); }
__device__ __forceinline__ unsigned short cvt_bf16(float x){
  unsigned u = __float_as_uint(x);
  u += 0x7FFFu + ((u >> 16) & 1u);
  return (unsigned short)(u >> 16);
}
__device__ __forceinline__ unsigned pack2bf(float lo, float hi){
  return ((unsigned)cvt_bf16(hi) << 16) | (unsigned)cvt_bf16(lo);
}

__device__ __forceinline__ float bredSum(float v, float* red){
  #pragma unroll
  for (int m = 32; m >= 1; m >>= 1) v += __shfl_xor(v, m);
  __syncthreads();
  if ((threadIdx.x & 63) == 0) red[threadIdx.x >> 6] = v;
  __syncthreads();
  float r = 0.f;
  int nw = blockDim.x >> 6;
  for (int k = 0; k < nw; ++k) r += red[k];
  return r;
}

// ---------------- prep (transposes/zero) + enc_base merged into one dispatch ----------------
__global__ __launch_bounds__(256) void k_prep_enc(const float* __restrict__ w_hh0,
    const float* __restrict__ w_ih1, const float* __restrict__ w_hh1,
    const float* __restrict__ W_attn, const float* __restrict__ W_v1,
    const float* __restrict__ W_reduce, const float* __restrict__ enc,
    const float* __restrict__ b_attn, float* __restrict__ ws){
  int bx = blockIdx.x, tid = threadIdx.x;
  __shared__ float tile[64*65];
  __shared__ float encs[16][132];
  __shared__ float was[50][132];
  if (bx < 627){
    if (bx < 192){
      int m = bx >> 6, t6 = bx & 63;
      int kb = t6 & 3, cb = t6 >> 2;
      const float* src = (m == 0) ? w_hh0 : (m == 1) ? w_ih1 : w_hh1;
      int dstoff = (m == 0) ? WS_WT0 : (m == 1) ? WS_WTI1 : WS_WTH1;
      for (int o = tid; o < 4096; o += 256){
        int cc = o >> 6, kk = o & 63;
        int c = cb*64 + cc;
        int j = (c & 3)*256 + (c >> 2);
        tile[cc*65 + kk] = src[j*256 + kb*64 + kk];
      }
      __syncthreads();
      for (int o = tid; o < 4096; o += 256){
        int kk = o >> 6, cc = o & 63;
        ws[dstoff + (kb*64 + kk)*1024 + cb*64 + cc] = tile[cc*65 + kk];
      }
      return;
    }
    if (bx < 224){
      int t6 = bx - 192;      // W_reduce [256 j][512 k] -> WRT [512 k][256 j]
      int kb = t6 & 7, jb = t6 >> 3;
      for (int o = tid; o < 4096; o += 256){
        int jj = o >> 6, kk = o & 63;
        tile[jj*65 + kk] = W_reduce[(jb*64 + jj)*512 + kb*64 + kk];
      }
      __syncthreads();
      for (int o = tid; o < 4096; o += 256){
        int kk = o >> 6, jj = o & 63;
        ws[WS_WRT + (kb*64 + kk)*256 + jb*64 + jj] = tile[jj*65 + kk];
      }
      return;
    }
    int i = (bx - 224)*256 + tid;
    if (i < 25600){ int k = i/100, a = i%100; ws[WS_WODT + i] = W_attn[a*769 + 512 + k]; return; }
    i -= 25600;
    if (i < 76800){ int k = i/100, f = i%100; ws[WS_WV1T + i] = W_v1[f*768 + k]; return; }
    i -= 76800;
    if (i < 512){ ws[WS_VSUM + i] = 0.f; return; }
    return;
  }
  // ---- enc_base: packed bf16 [b][p2][s], value = (enc@Wattn + b_attn)*2log2e ----
  int r = bx - 627;                      // 800 = st + 25*(ah + 2*b)
  int st = r % 25, rem = r / 25;
  int ah = rem & 1, b = rem >> 1;
  int s_base = st*16;
  bool act = tid < 200;
  int sg = tid & 7, ag = tid >> 3;
  int sl = sg*2, al = ag*2;
  float acc00=0.f, acc01=0.f, acc10=0.f, acc11=0.f;
  for (int kc = 0; kc < 4; ++kc){
    int k0 = kc*128;
    __syncthreads();
    for (int o = tid; o < 512; o += 256){
      int rr = o >> 5, c4 = (o & 31)*4;
      float4 v = *(const float4*)(enc + ((s_base + rr)*B_ + b)*512 + k0 + c4);
      *(float4*)&encs[rr][c4] = v;
    }
    for (int o = tid; o < 6400; o += 256){
      int rr = o >> 7, c = o & 127;
      was[rr][c] = W_attn[(ah*50 + rr)*769 + k0 + c];
    }
    __syncthreads();
    if (act){
      for (int k = 0; k < 128; ++k){
        float e0 = encs[sl][k], e1 = encs[sl+1][k];
        float w0 = was[al][k],  w1 = was[al+1][k];
        acc00 = fmaf(e0, w0, acc00); acc01 = fmaf(e0, w1, acc01);
        acc10 = fmaf(e1, w0, acc10); acc11 = fmaf(e1, w1, acc11);
      }
    }
  }
  if (act){
    int a = ah*50 + al, s = s_base + sl;
    float b0 = b_attn[a], b1 = b_attn[a+1];
    int p2 = ah*25 + (al >> 1);
    unsigned* bu = (unsigned*)(ws + WS_BASE2) + b*20000;
    bu[p2*400 + s    ] = pack2bf((acc00 + b0)*L2E2, (acc01 + b1)*L2E2);
    bu[p2*400 + s + 1] = pack2bf((acc10 + b0)*L2E2, (acc11 + b1)*L2E2);
  }
}

// ---------------- encoder state reduce (writes h-major state) ----------------
__global__ __launch_bounds__(256) void k_reduce_enc(const float* __restrict__ he,
    const float* __restrict__ ce, const float* __restrict__ b_reduce, float* __restrict__ ws){
  int bx = blockIdx.x;            // 32 blocks: l = bx>>4, b = bx&15
  int l = bx >> 4, b = bx & 15, j = threadIdx.x;
  const float* wrt = ws + WS_WRT;
  const float* h_a = he + (l*B_ + b)*H_;
  const float* h_b = he + ((l+2)*B_ + b)*H_;
  const float* c_a = ce + (l*B_ + b)*H_;
  const float* c_b = ce + ((l+2)*B_ + b)*H_;
  float ah = b_reduce[j], ac = b_reduce[j];
  for (int k = 0; k < 256; ++k){
    float w0 = wrt[k*256 + j];
    float w1 = wrt[(256+k)*256 + j];
    ah += w0*h_a[k] + w1*h_b[k];
    ac += w0*c_a[k] + w1*c_b[k];
  }
  if (l == 0){ ws[WS_H0S + j*16 + b] = ah; ws[WS_C0S + j*16 + b] = ac; }
  else       { ws[WS_H1S + j*16 + b] = ah; ws[WS_C1S + j*16 + b] = ac; }
}

// ---------------- LSTM phase p: WGs 0-31 layer0 step p, WGs 32-95 layer1 step p-1 ----------------
__global__ __launch_bounds__(256, 1) void k_lstm3(const float* __restrict__ input_dec,
    const float* __restrict__ w_ih0, const float* __restrict__ b_ih0, const float* __restrict__ b_hh0,
    const float* __restrict__ b_ih1, const float* __restrict__ b_hh1,
    float* __restrict__ ws, float* __restrict__ out, int p){
  int wgs = blockIdx.x;
  int tid = threadIdx.x;
  __shared__ float hs[4096];
  __shared__ float ys[4096];
  __shared__ float gv[576];
  __shared__ float xs[16];
  if (wgs < 32){
    if (p >= T_) return;
    int w = wgs;
    int par = p & 1, npar = par ^ 1;
    for (int o = tid; o < 1024; o += 256)
      *(float4*)&hs[o*4] = *(const float4*)&ws[WS_H0S + par*4096 + o*4];
    if (tid < 16) xs[tid] = input_dec[p*16 + tid];
    __syncthreads();
    int l5 = tid & 31, bg = tid >> 5;        // bg 0..7 -> batches bg*2, bg*2+1
    int c = w*32 + l5;
    int g = c & 3, h = c >> 2;               // h = w*8 + (l5>>2)
    int j = g*256 + h;
    float bias = b_ih0[j] + b_hh0[j];
    float wih = w_ih0[j];
    float a0 = fmaf(xs[bg*2],   wih, bias);
    float a1 = fmaf(xs[bg*2+1], wih, bias);
    const float* wp = ws + WS_WT0 + c;
    #pragma unroll 16
    for (int k = 0; k < 256; ++k){
      float wv = wp[k*1024];
      float2 hv = *(const float2*)&hs[k*16 + bg*2];
      a0 = fmaf(wv, hv.x, a0); a1 = fmaf(wv, hv.y, a1);
    }
    int hloc = l5 >> 2;
    gv[(g*8 + hloc)*18 + bg*2    ] = a0;
    gv[(g*8 + hloc)*18 + bg*2 + 1] = a1;
    __syncthreads();
    if (tid < 128){
      int b = tid & 15, h2 = tid >> 4;       // h2 0..7
      float gi = gv[(0*8+h2)*18 + b], gf = gv[(1*8+h2)*18 + b];
      float gg = gv[(2*8+h2)*18 + b], go = gv[(3*8+h2)*18 + b];
      int hidx = w*8 + h2;
      float cold = ws[WS_C0S + par*4096 + hidx*16 + b];
      float ig = sigm(gi), fg = sigm(gf), gt = tanhx(gg), og = sigm(go);
      float cn = fmaf(fg, cold, ig*gt);
      float hn = og * tanhx(cn);
      ws[WS_C0S + npar*4096 + hidx*16 + b] = cn;
      ws[WS_H0S + npar*4096 + hidx*16 + b] = hn;
      ws[WS_Y0 + p*4096 + hidx*16 + b] = hn;
      if (p == T_-1){
        out[OUT_HID  + b*256 + hidx] = hn;
        out[OUT_CELL + b*256 + hidx] = cn;
      }
    }
  } else {
    int q = p - 1;
    if (q < 0) return;
    int u = wgs - 32;                        // 0..63
    int par = q & 1, npar = par ^ 1;
    for (int o = tid; o < 1024; o += 256){
      *(float4*)&ys[o*4] = *(const float4*)&ws[WS_Y0 + q*4096 + o*4];
      *(float4*)&hs[o*4] = *(const float4*)&ws[WS_H1S + par*4096 + o*4];
    }
    __syncthreads();
    int l4 = tid & 15, b = tid >> 4;         // 16 batches, 1 each
    int c = u*16 + l4;
    int g = c & 3, h = c >> 2;               // h = u*4 + (l4>>2)
    int j = g*256 + h;
    float ai = b_ih1[j] + b_hh1[j];
    float ah2 = 0.f;
    const float* wi = ws + WS_WTI1 + c;
    const float* wh = ws + WS_WTH1 + c;
    #pragma unroll 16
    for (int k = 0; k < 256; ++k){
      ai  = fmaf(wi[k*1024], ys[k*16 + b], ai);
      ah2 = fmaf(wh[k*1024], hs[k*16 + b], ah2);
    }
    int hloc = l4 >> 2;
    gv[(g*4 + hloc)*17 + b] = ai + ah2;
    __syncthreads();
    if (tid < 64){
      int b2 = tid & 15, h2 = tid >> 4;      // h2 0..3
      float gi = gv[(0*4+h2)*17 + b2], gf = gv[(1*4+h2)*17 + b2];
      float gg = gv[(2*4+h2)*17 + b2], go = gv[(3*4+h2)*17 + b2];
      int hidx = u*4 + h2;
      float cold = ws[WS_C1S + par*4096 + hidx*16 + b2];
      float ig = sigm(gi), fg = sigm(gf), gt = tanhx(gg), og = sigm(go);
      float cn = fmaf(fg, cold, ig*gt);
      float hn = og * tanhx(cn);
      ws[WS_C1S + npar*4096 + hidx*16 + b2] = cn;
      ws[WS_H1S + npar*4096 + hidx*16 + b2] = hn;
      ws[WS_OD + q*4096 + hidx*16 + b2] = hn;
      if (q == T_-1){
        out[OUT_HID  + 4096 + b2*256 + hidx] = hn;
        out[OUT_CELL + 4096 + b2*256 + hidx] = cn;
      }
    }
  }
}

// ---------------- odp2[t*16+b][a] = (od @ W_attn[:,512:768]^T) * 2log2e ----------------
__global__ __launch_bounds__(256) void k_odp(float* __restrict__ ws){
  int row = blockIdx.x;        // 512 = t*16+b
  int t = row >> 4, b = row & 15;
  int tid = threadIdx.x;
  __shared__ float odl[256];
  odl[tid] = ws[WS_OD + t*4096 + tid*16 + b];
  __syncthreads();
  if (tid < 100){
    float acc = 0.f;
    for (int k = 0; k < 256; ++k) acc = fmaf(ws[WS_WODT + k*100 + tid], odl[k], acc);
    ws[WS_ODP2 + row*100 + tid] = acc * L2E2;
  }
}

// ---------------- attention recurrence v5: one WG per batch, base2 in LDS (bf16-packed),
// LDS-f4 odp prefetch, cov in registers, 2 barriers/step ----------------
__global__ __launch_bounds__(1024) void k_attn(const float* __restrict__ amask,
    const float* __restrict__ W_attn, const float* __restrict__ wout_g,
    float* __restrict__ out, float* __restrict__ ws){
  int b = blockIdx.x;
  int tid = threadIdx.x;
  int wv = tid >> 6, l = tid & 63;
  int half = wv & 1, sblk = wv >> 1;
  int s = sblk*64 + l;
  bool valid = (sblk < 7) && (s < 400);
  bool even = (half == 0);
  int h25 = half*25, a0 = half*50;
  __shared__ unsigned ba2L[20000];        // [p2 0..49][s 0..399] packed bf16 pair
  __shared__ float eh[2][400];
  __shared__ float4 f4[2][100];
  __shared__ float wcwo[200];
  __shared__ float den[2], cls[2];
  const unsigned* src = (const unsigned*)(ws + WS_BASE2) + b*20000;
  for (int o = tid; o < 20000; o += 1024) ba2L[o] = src[o];
  if (tid < 100){
    wcwo[tid]       = W_attn[tid*769 + 768] * L2E2;
    wcwo[100 + tid] = -2.f * wout_g[tid];
  }
  if (tid < 2){ den[tid] = 0.f; cls[tid] = 0.f; }
  __syncthreads();
  float woSum = 0.f;
  #pragma unroll 10
  for (int a = 0; a < 100; ++a) woSum -= 0.5f * wcwo[100 + a];
  float amL = valid ? amask[s*16 + b] * L2E : 0.f;
  float cov = 0.f;
  int sI = valid ? s : 0;
  if (tid < 100){
    float od = ws[WS_ODP2 + b*100 + tid];   // t=0 row
    f4[0][tid] = make_float4(od, wcwo[tid], wcwo[100 + tid], 0.f);
  }
  __syncthreads();

  for (int t = 0; t < T_; ++t){
    int par = t & 1;
    if (valid){
      float ep0 = 0.f, ep1 = 0.f;
      #pragma unroll
      for (int i2 = 0; i2 < 25; ++i2){
        unsigned d = ba2L[(h25 + i2)*400 + sI];
        float4 qa = f4[par][a0 + 2*i2];
        float4 qb = f4[par][a0 + 2*i2 + 1];
        float blo = __uint_as_float(d << 16);
        float bhi = __uint_as_float(d & 0xffff0000u);
        float xa = fmaf(qa.y, cov, blo + qa.x);
        float xb = fmaf(qb.y, cov, bhi + qb.x);
        ep0 = fmaf(qa.z, frcp(1.f + fexp2(xa)), ep0);
        ep1 = fmaf(qb.z, frcp(1.f + fexp2(xb)), ep1);
      }
      eh[half][s] = ep0 + ep1;
    }
    __syncthreads();                      // A: eh ready
    float ex = 0.f;
    if (valid){
      float et = woSum + eh[0][s] + eh[1][s];
      ex = fexp2(fmaf(et, L2E, amL));
    }
    float ps = ex;
    #pragma unroll
    for (int m = 32; m >= 1; m >>= 1) ps += __shfl_xor(ps, m);
    if (even && l == 0) atomicAdd(&den[par], ps);
    if (tid < 100 && t < T_-1){
      float od = ws[WS_ODP2 + ((t+1)*16 + b)*100 + tid];
      f4[par^1][tid] = make_float4(od, wcwo[tid], wcwo[100 + tid], 0.f);
    }
    if (tid == 0 && t > 0){
      out[OUT_CL + (t-1)*16 + b] = cls[par^1];
      cls[par^1] = 0.f;
      den[par^1] = 0.f;
    }
    __syncthreads();                      // B: den ready
    float inv = frcp(den[par]);
    float at = ex * inv;
    float cl = fminf(at, cov);
    cov += at;
    float p2 = cl;
    #pragma unroll
    for (int m = 32; m >= 1; m >>= 1) p2 += __shfl_xor(p2, m);
    if (even && l == 0) atomicAdd(&cls[par], p2);
    if (even && valid) ws[WS_ATTN + (b*32 + t)*400 + s] = at;
  }
  __syncthreads();
  if (tid == 0) out[OUT_CL + 31*16 + b] = cls[1];
  if (even && valid) out[OUT_COV + s*16 + b] = cov;
}

// ---------------- context partials into out-scratch: ctxp[sc][t*16+b][512] ----------------
__global__ __launch_bounds__(256) void k_ctx(const float* __restrict__ enc,
    const float* __restrict__ ws, float* __restrict__ ctxp){
  int b = blockIdx.x, jh = blockIdx.y, sc = blockIdx.z;   // (16,2,8)
  int tid = threadIdx.x;
  __shared__ float at[32*52];
  for (int o = tid; o < 1600; o += 256){
    int t = o/50, s2 = o%50;
    at[t*52 + s2] = ws[WS_ATTN + (b*32 + t)*400 + sc*50 + s2];
  }
  __syncthreads();
  int j = jh*256 + tid;
  float acc[32];
  #pragma unroll
  for (int t = 0; t < 32; ++t) acc[t] = 0.f;
  for (int s2 = 0; s2 < 50; ++s2){
    float evv = enc[((sc*50 + s2)*16 + b)*512 + j];
    #pragma unroll
    for (int t = 0; t < 32; ++t) acc[t] = fmaf(at[t*52 + s2], evv, acc[t]);
  }
  #pragma unroll
  for (int t = 0; t < 32; ++t)
    ctxp[sc*CTXP_SZ + (t*16 + b)*512 + j] = acc[t];
}

// ---------------- pgen + h1 (vocab hidden, bf16 padded) per (t,b) ----------------
__global__ __launch_bounds__(256) void k_pgen_h1(const float* __restrict__ input_dec,
    const float* __restrict__ emb, const float* __restrict__ b_v1,
    const float* __restrict__ W_pgen, const float* __restrict__ b_pgen,
    const float* __restrict__ ctxp, float* __restrict__ ws){
  int row = blockIdx.x, tid = threadIdx.x;
  int t = row >> 4, b = row & 15;
  __shared__ float pv[768], el[50], red[16];
  pv[tid] = ws[WS_OD + t*4096 + tid*16 + b];
  float c0 = 0.f, c1 = 0.f;
  #pragma unroll
  for (int sc = 0; sc < 8; ++sc){
    c0 += ctxp[sc*CTXP_SZ + row*512 + tid];
    c1 += ctxp[sc*CTXP_SZ + row*512 + 256 + tid];
  }
  pv[256 + tid] = c0;
  pv[512 + tid] = c1;
  int tok = (int)input_dec[row];
  if (tid < 50) el[tid] = emb[tok*50 + tid];
  __syncthreads();
  float p = 0.f;
  for (int k = tid; k < 818; k += 256){
    float x = (k < 512) ? pv[256 + k] : (k < 768) ? pv[k - 512] : el[k - 768];
    p = fmaf(W_pgen[k], x, p);
  }
  p = bredSum(p, red);
  if (tid == 0) ws[WS_PGEN + row] = sigm(p + b_pgen[0]);
  short* hb = (short*)(ws + WS_H1B);
  if (tid < 100){
    float acc = b_v1[tid];
    for (int k = 0; k < 768; ++k) acc = fmaf(ws[WS_WV1T + k*100 + tid], pv[k], acc);
    hb[row*128 + tid] = (short)cvt_bf16(acc);
  } else if (tid < 128){
    hb[row*128 + tid] = 0;
  }
}

// ---------------- vocab GEMM via MFMA: shared frag loader ----------------
__device__ __forceinline__ void load_bfrags(const float* __restrict__ W_v2,
    const float* __restrict__ b_v2, int v0, int lane_m, int lq,
    bf16x8 bf[4][4], float bias[4], int vv[4]){
  #pragma unroll
  for (int nt = 0; nt < 4; ++nt){
    int v = v0 + nt*16 + lane_m;
    vv[nt] = v;
    bool vok = v < V_;
    bias[nt] = vok ? b_v2[v] : 0.f;
    const float* wp = W_v2 + (size_t)v*100;
    #pragma unroll
    for (int kk = 0; kk < 4; ++kk){
      int k0 = kk*32 + lq*8;
      float x[8];
      if (vok && kk < 3){
        float4 p0 = *(const float4*)(wp + k0);
        float4 p1 = *(const float4*)(wp + k0 + 4);
        x[0]=p0.x; x[1]=p0.y; x[2]=p0.z; x[3]=p0.w;
        x[4]=p1.x; x[5]=p1.y; x[6]=p1.z; x[7]=p1.w;
      } else if (vok && k0 == 96){
        float4 p0 = *(const float4*)(wp + 96);
        x[0]=p0.x; x[1]=p0.y; x[2]=p0.z; x[3]=p0.w;
        x[4]=0.f; x[5]=0.f; x[6]=0.f; x[7]=0.f;
      } else {
        #pragma unroll
        for (int e = 0; e < 8; ++e) x[e] = 0.f;
      }
      bf16x8 r;
      #pragma unroll
      for (int e = 0; e < 8; ++e) r[e] = (short)cvt_bf16(x[e]);
      bf[nt][kk] = r;
    }
  }
}

// ---------------- pass A: per-row exp2-sums of logits (no materialization) ----------------
__global__ __launch_bounds__(256) void k_vsum(const float* __restrict__ W_v2,
    const float* __restrict__ b_v2, float* __restrict__ ws){
  int tid = threadIdx.x;
  int wave = tid >> 6, l = tid & 63;
  int lane_m = l & 15, lq = l >> 4;
  int v0 = blockIdx.x*256 + wave*64;
  int r0base = blockIdx.y*256;
  __shared__ float rsum[256];
  for (int o = tid; o < 256; o += 256) rsum[o] = 0.f;
  bf16x8 bf[4][4];
  float bias[4];
  int vv[4];
  load_bfrags(W_v2, b_v2, v0, lane_m, lq, bf, bias, vv);
  __syncthreads();
  const short* hws = (const short*)(ws + WS_H1B);
  for (int rg = 0; rg < 16; ++rg){
    int r0 = r0base + rg*16;
    bf16x8 af[4];
    #pragma unroll
    for (int kk = 0; kk < 4; ++kk)
      af[kk] = *(const bf16x8*)(hws + (r0 + lane_m)*128 + kk*32 + lq*8);
    float es[4] = {0.f, 0.f, 0.f, 0.f};
    #pragma unroll
    for (int nt = 0; nt < 4; ++nt){
      f32x4 c = {bias[nt], bias[nt], bias[nt], bias[nt]};
      #pragma unroll
      for (int kk = 0; kk < 4; ++kk)
        c = __builtin_amdgcn_mfma_f32_16x16x32_bf16(af[kk], bf[nt][kk], c, 0, 0, 0);
      if (vv[nt] < V_){
        #pragma unroll
        for (int j = 0; j < 4; ++j) es[j] += fexp2(c[j] * L2E);
      }
    }
    #pragma unroll
    for (int m = 1; m <= 8; m <<= 1){
      #pragma unroll
      for (int j = 0; j < 4; ++j) es[j] += __shfl_xor(es[j], m);
    }
    if (lane_m == 0){
      #pragma unroll
      for (int j = 0; j < 4; ++j)
        atomicAdd(&rsum[rg*16 + lq*4 + j], es[j]);
    }
  }
  __syncthreads();
  if (tid < 256) atomicAdd(ws + WS_VSUM + r0base + tid, rsum[tid]);
}

// ---------------- pass B: recompute logits, write softmax*pgen via LDS-staged coalesced stores ----------------
__global__ __launch_bounds__(256) void k_vwrite(const float* __restrict__ W_v2,
    const float* __restrict__ b_v2, const float* __restrict__ ws, float* __restrict__ out){
  int tid = threadIdx.x;
  int wave = tid >> 6, l = tid & 63;
  int lane_m = l & 15, lq = l >> 4;
  int vblock0 = blockIdx.x*256;
  int v0 = vblock0 + wave*64;
  int r0base = blockIdx.y*128;
  __shared__ float scs[128];
  __shared__ float stg[16][260];
  if (tid < 128){
    int r = r0base + tid;
    scs[tid] = ws[WS_PGEN + r] / ws[WS_VSUM + r];
  }
  bf16x8 bf[4][4];
  float bias[4];
  int vv[4];
  load_bfrags(W_v2, b_v2, v0, lane_m, lq, bf, bias, vv);
  __syncthreads();
  const short* hws = (const short*)(ws + WS_H1B);
  int limit = BV_ - vblock0;            // valid col count in [0,256]
  if (limit > 256) limit = 256;
  for (int rg = 0; rg < 8; ++rg){
    int r0 = r0base + rg*16;
    bf16x8 af[4];
    #pragma unroll
    for (int kk = 0; kk < 4; ++kk)
      af[kk] = *(const bf16x8*)(hws + (r0 + lane_m)*128 + kk*32 + lq*8);
    #pragma unroll
    for (int nt = 0; nt < 4; ++nt){
      f32x4 c = {bias[nt], bias[nt], bias[nt], bias[nt]};
      #pragma unroll
      for (int kk = 0; kk < 4; ++kk)
        c = __builtin_amdgcn_mfma_f32_16x16x32_bf16(af[kk], bf[nt][kk], c, 0, 0, 0);
      bool gen = vv[nt] < V_;
      #pragma unroll
      for (int j = 0; j < 4; ++j){
        int rloc = lq*4 + j;
        float p = gen ? fexp2(c[j] * L2E) * scs[rg*16 + rloc] : 0.f;
        stg[rloc][wave*64 + nt*16 + lane_m] = p;
      }
    }
    __syncthreads();
    #pragma unroll
    for (int rep = 0; rep < 4; ++rep){
      int o = rep*256 + tid;
      int rr = o >> 6, c4 = (o & 63)*4;
      size_t base = (size_t)(r0base + rg*16 + rr)*BV_ + vblock0;
      if (c4 + 4 <= limit){
        float4 val = *(const float4*)&stg[rr][c4];
        *(float4*)&out[base + c4] = val;
      } else {
        for (int e = 0; e < 4; ++e)
          if (c4 + e < limit) out[base + c4 + e] = stg[rr][c4 + e];
      }
    }
    __syncthreads();
  }
}

// ---------------- copy-distribution scatter ----------------
__global__ __launch_bounds__(256) void k_scatter(const int* __restrict__ real_index,
    const float* __restrict__ ws, float* __restrict__ out){
  int i = blockIdx.x*256 + threadIdx.x;   // 16*32*400
  int b = i / 12800, r = i % 12800, t = r / 400, s = r % 400;
  float at = ws[WS_ATTN + i];
  float w = 1.f - ws[WS_PGEN + t*16 + b];
  int col = real_index[s*16 + b];
  atomicAdd(out + (size_t)(t*16 + b)*BV_ + col, at*w);
}

extern "C" void kernel_launch(void* const* d_in, const int* in_sizes, int n_in,
                              void* d_out, int out_size, void* d_ws, size_t ws_size,
                              hipStream_t stream){
  const float* output_enc = (const float*)d_in[0];
  const int*   real_index = (const int*)d_in[1];
  const float* input_dec  = (const float*)d_in[3];
  const float* hidden_enc = (const float*)d_in[4];
  const float* cell_enc   = (const float*)d_in[5];
  const float* att_mask   = (const float*)d_in[6];
  const float* emb        = (const float*)d_in[7];
  const float* W_reduce   = (const float*)d_in[8];
  const float* b_reduce   = (const float*)d_in[9];
  const float* w_ih0      = (const float*)d_in[10];
  const float* w_hh0      = (const float*)d_in[11];
  const float* b_ih0      = (const float*)d_in[12];
  const float* b_hh0      = (const float*)d_in[13];
  const float* w_ih1      = (const float*)d_in[14];
  const float* w_hh1      = (const float*)d_in[15];
  const float* b_ih1      = (const float*)d_in[16];
  const float* b_hh1      = (const float*)d_in[17];
  const float* W_attn     = (const float*)d_in[18];
  const float* b_attn     = (const float*)d_in[19];
  const float* w_attn_out = (const float*)d_in[20];
  const float* W_v1       = (const float*)d_in[21];
  const float* b_v1       = (const float*)d_in[22];
  const float* W_v2       = (const float*)d_in[23];
  const float* b_v2       = (const float*)d_in[24];
  const float* W_pgen     = (const float*)d_in[25];
  const float* b_pgen     = (const float*)d_in[26];
  float* out = (float*)d_out;
  float* ws  = (float*)d_ws;
  if (ws_size < (size_t)WS_TOTAL * sizeof(float)) return;

  k_prep_enc<<<dim3(1427), dim3(256), 0, stream>>>(w_hh0, w_ih1, w_hh1, W_attn, W_v1,
                                                   W_reduce, output_enc, b_attn, ws);
  k_reduce_enc<<<dim3(32), dim3(256), 0, stream>>>(hidden_enc, cell_enc, b_reduce, ws);
  for (int p = 0; p <= T_; ++p)
    k_lstm3<<<dim3(96), dim3(256), 0, stream>>>(input_dec, w_ih0, b_ih0, b_hh0,
                                                b_ih1, b_hh1, ws, out, p);
  k_odp<<<dim3(512), dim3(256), 0, stream>>>(ws);
  k_attn<<<dim3(16), dim3(1024), 0, stream>>>(att_mask, W_attn, w_attn_out, out, ws);
  k_ctx<<<dim3(16, 2, 8), dim3(256), 0, stream>>>(output_enc, ws, out);
  k_pgen_h1<<<dim3(512), dim3(256), 0, stream>>>(input_dec, emb, b_v1, W_pgen, b_pgen, out, ws);
  k_vsum<<<dim3(196, 2), dim3(256), 0, stream>>>(W_v2, b_v2, ws);
  k_vwrite<<<dim3(196, 4), dim3(256), 0, stream>>>(W_v2, b_v2, ws, out);
  k_scatter<<<dim3(800), dim3(256), 0, stream>>>(real_index, ws, out);
}